// Round 4
// baseline (542.041 us; speedup 1.0000x reference)
//
#include <hip/hip_runtime.h>

using u16 = unsigned short;
using u32 = unsigned int;
typedef __bf16 bf16;
typedef bf16 bf16x8 __attribute__((ext_vector_type(8)));
typedef u16 u16x8 __attribute__((ext_vector_type(8)));
typedef float f32x4 __attribute__((ext_vector_type(4)));

// Problem constants: B=4, T=2048, E=1024, H=16, D=64
// Inputs fp32, output fp32 (reference dtypes). Internals bf16 (MFMA).
#define LDSS 72   // LDS row stride in bf16 elems: 144B rows, 16B-aligned, <=2-way bank conflicts

__device__ __forceinline__ u16 f2bf(float f) {
  u32 u = __builtin_bit_cast(u32, f);
  u += 0x7FFFu + ((u >> 16) & 1u);   // round-to-nearest-even
  return (u16)(u >> 16);
}

__device__ __forceinline__ bf16x8 ldfrag(const u16* p) {
  return __builtin_bit_cast(bf16x8, *(const u16x8*)p);
}

__device__ __forceinline__ u16x8 cvt8(const float* p) {
  float4 a = ((const float4*)p)[0];
  float4 b = ((const float4*)p)[1];
  u16x8 o;
  o[0] = f2bf(a.x); o[1] = f2bf(a.y); o[2] = f2bf(a.z); o[3] = f2bf(a.w);
  o[4] = f2bf(b.x); o[5] = f2bf(b.y); o[6] = f2bf(b.z); o[7] = f2bf(b.w);
  return o;
}

// ---------------------------------------------------------------------------
// QKV projection: qkv[m][f] = sum_c x[m][c] * W_qkv[f][c]
// M=8192 (b,t), N=3072 (f), K=1024. fp32 sources converted in staging.
// Epilogue scatters: Q -> [B,H,T,D] (scaled 0.125), K -> [B,H,T,D],
//                    V -> transposed [B,H,D,T]   (all bf16)
// ---------------------------------------------------------------------------
__global__ __launch_bounds__(256) void qkv_gemm(
    const float* __restrict__ X, const float* __restrict__ W,
    u16* __restrict__ Qw, u16* __restrict__ Kw, u16* __restrict__ Vtw) {
  __shared__ u16 As[128 * LDSS];
  __shared__ u16 Bs[128 * LDSS];
  const int tid = threadIdx.x;
  const int lane = tid & 63;
  const int wv = tid >> 6;
  const int quad = lane >> 4;
  const int l16 = lane & 15;
  const int m0 = (wv >> 1) * 64;
  const int n0 = (wv & 1) * 64;
  const int rowA0 = blockIdx.y * 128;
  const int rowB0 = blockIdx.x * 128;

  f32x4 acc[4][4] = {};

  for (int kt = 0; kt < 1024; kt += 64) {
#pragma unroll
    for (int t = 0; t < 4; ++t) {
      int ch = tid + t * 256;
      int row = ch >> 3, cb = ch & 7;
      *(u16x8*)&As[row * LDSS + cb * 8] =
          cvt8(&X[(size_t)(rowA0 + row) * 1024 + kt + cb * 8]);
      *(u16x8*)&Bs[row * LDSS + cb * 8] =
          cvt8(&W[(size_t)(rowB0 + row) * 1024 + kt + cb * 8]);
    }
    __syncthreads();
#pragma unroll
    for (int kk = 0; kk < 64; kk += 32) {
      bf16x8 af[4], bfr[4];
#pragma unroll
      for (int i = 0; i < 4; ++i)
        af[i] = ldfrag(&As[(m0 + i * 16 + l16) * LDSS + kk + quad * 8]);
#pragma unroll
      for (int j = 0; j < 4; ++j)
        bfr[j] = ldfrag(&Bs[(n0 + j * 16 + l16) * LDSS + kk + quad * 8]);
#pragma unroll
      for (int i = 0; i < 4; ++i)
#pragma unroll
        for (int j = 0; j < 4; ++j)
          acc[i][j] = __builtin_amdgcn_mfma_f32_16x16x32_bf16(af[i], bfr[j], acc[i][j], 0, 0, 0);
    }
    __syncthreads();
  }

#pragma unroll
  for (int i = 0; i < 4; ++i)
#pragma unroll
    for (int j = 0; j < 4; ++j)
#pragma unroll
      for (int r = 0; r < 4; ++r) {
        int m = rowA0 + m0 + i * 16 + quad * 4 + r;   // C row
        int f = rowB0 + n0 + j * 16 + l16;            // C col
        float v = acc[i][j][r];
        int bb = m >> 11, t = m & 2047;
        int part = f >> 10, fi = f & 1023;
        int h = fi >> 6, d = fi & 63;
        if (part == 0) {
          Qw[((size_t)(bb * 16 + h) * 2048 + t) * 64 + d] = f2bf(v * 0.125f);
        } else if (part == 1) {
          Kw[((size_t)(bb * 16 + h) * 2048 + t) * 64 + d] = f2bf(v);
        } else {
          Vtw[((size_t)(bb * 16 + h) * 64 + d) * 2048 + t] = f2bf(v);
        }
      }
}

// ---------------------------------------------------------------------------
// Flash attention: per block = one (b,h) and one 128-row Q tile.
// 4 waves, each owns a 32-row stripe. K-tiles of 64 keys, online softmax.
// Q pre-scaled by 0.125. V is stored transposed [D][T] for contiguous B-frags.
// ---------------------------------------------------------------------------
__global__ __launch_bounds__(256) void attn_kernel(
    const u16* __restrict__ Qw, const u16* __restrict__ Kw,
    const u16* __restrict__ Vtw, u16* __restrict__ Ao) {
  __shared__ u16 Ks[64 * LDSS];
  __shared__ u16 Vs[64 * LDSS];
  __shared__ u16 Ps[128 * LDSS];
  const int tid = threadIdx.x;
  const int lane = tid & 63;
  const int wv = tid >> 6;
  const int quad = lane >> 4;
  const int l16 = lane & 15;
  const int qt = blockIdx.x & 15;
  const int bh = blockIdx.x >> 4;
  const u16* Qb = Qw + (size_t)bh * 2048 * 64;
  const u16* Kb = Kw + (size_t)bh * 2048 * 64;
  const u16* Vb = Vtw + (size_t)bh * 64 * 2048;
  const int qrow0 = qt * 128 + wv * 32;

  // Q fragments held in registers for the whole block
  bf16x8 qf[2][2];
#pragma unroll
  for (int i = 0; i < 2; ++i)
#pragma unroll
    for (int kk = 0; kk < 2; ++kk)
      qf[i][kk] = __builtin_bit_cast(bf16x8,
          *(const u16x8*)&Qb[(size_t)(qrow0 + i * 16 + l16) * 64 + kk * 32 + quad * 8]);

  f32x4 oacc[2][4] = {};
  float mst[2][4], lst[2][4];
#pragma unroll
  for (int i = 0; i < 2; ++i)
#pragma unroll
    for (int r = 0; r < 4; ++r) { mst[i][r] = -INFINITY; lst[i][r] = 0.f; }

  const float LOG2E = 1.4426950408889634f;
  const int nkt = 2 * qt + 2;
  for (int kt = 0; kt < nkt; ++kt) {
    // stage full 64x64 K and V tiles: 512 8-elem chunks each, 2 per thread
#pragma unroll
    for (int t = 0; t < 2; ++t) {
      int ch = tid + t * 256;          // [0,512)
      int row = ch >> 3, cb = ch & 7;
      *(u16x8*)&Ks[row * LDSS + cb * 8] =
          *(const u16x8*)&Kb[(size_t)(kt * 64 + row) * 64 + cb * 8];
      *(u16x8*)&Vs[row * LDSS + cb * 8] =
          *(const u16x8*)&Vb[(size_t)row * 2048 + kt * 64 + cb * 8];
    }
    __syncthreads();

    // S = Q . K^T  (32 x 64 per wave)
    f32x4 s[2][4] = {};
#pragma unroll
    for (int kk = 0; kk < 2; ++kk) {
      bf16x8 bk[4];
#pragma unroll
      for (int j = 0; j < 4; ++j)
        bk[j] = ldfrag(&Ks[(j * 16 + l16) * LDSS + kk * 32 + quad * 8]);
#pragma unroll
      for (int i = 0; i < 2; ++i)
#pragma unroll
        for (int j = 0; j < 4; ++j)
          s[i][j] = __builtin_amdgcn_mfma_f32_16x16x32_bf16(qf[i][kk], bk[j], s[i][j], 0, 0, 0);
    }

    // causal mask (only the last two K-tiles can touch the diagonal)
    if (kt >= 2 * qt) {
#pragma unroll
      for (int i = 0; i < 2; ++i)
#pragma unroll
        for (int j = 0; j < 4; ++j)
#pragma unroll
          for (int r = 0; r < 4; ++r) {
            int rg = qrow0 + i * 16 + quad * 4 + r;
            int cg = kt * 64 + j * 16 + l16;
            if (cg > rg) s[i][j][r] = -INFINITY;
          }
    }

    // online softmax per row; rows live across 16-lane groups
#pragma unroll
    for (int i = 0; i < 2; ++i)
#pragma unroll
      for (int r = 0; r < 4; ++r) {
        float mx = fmaxf(fmaxf(s[i][0][r], s[i][1][r]), fmaxf(s[i][2][r], s[i][3][r]));
        mx = fmaxf(mx, __shfl_xor(mx, 1));
        mx = fmaxf(mx, __shfl_xor(mx, 2));
        mx = fmaxf(mx, __shfl_xor(mx, 4));
        mx = fmaxf(mx, __shfl_xor(mx, 8));
        float mnew = fmaxf(mst[i][r], mx);
        float alpha = exp2f((mst[i][r] - mnew) * LOG2E);
        float rs = 0.f;
#pragma unroll
        for (int j = 0; j < 4; ++j) {
          float p = exp2f((s[i][j][r] - mnew) * LOG2E);
          s[i][j][r] = p;
          rs += p;
        }
        rs += __shfl_xor(rs, 1);
        rs += __shfl_xor(rs, 2);
        rs += __shfl_xor(rs, 4);
        rs += __shfl_xor(rs, 8);
        lst[i][r] = lst[i][r] * alpha + rs;
        mst[i][r] = mnew;
#pragma unroll
        for (int j = 0; j < 4; ++j) oacc[i][j][r] *= alpha;
        // P: C-layout -> LDS (row-major, k-contiguous) for A-operand reload
#pragma unroll
        for (int j = 0; j < 4; ++j)
          Ps[(wv * 32 + i * 16 + quad * 4 + r) * LDSS + j * 16 + l16] = f2bf(s[i][j][r]);
      }
    __syncthreads();   // P visibility

    // O += P . V   (A = P [32 x 64], B = V [64 keys x 64 d] via Vt tile)
#pragma unroll
    for (int kk = 0; kk < 2; ++kk) {
      bf16x8 ap[2], bv[4];
#pragma unroll
      for (int i = 0; i < 2; ++i)
        ap[i] = ldfrag(&Ps[(wv * 32 + i * 16 + l16) * LDSS + kk * 32 + quad * 8]);
#pragma unroll
      for (int j = 0; j < 4; ++j)
        bv[j] = ldfrag(&Vs[(j * 16 + l16) * LDSS + kk * 32 + quad * 8]);
#pragma unroll
      for (int i = 0; i < 2; ++i)
#pragma unroll
        for (int j = 0; j < 4; ++j)
          oacc[i][j] = __builtin_amdgcn_mfma_f32_16x16x32_bf16(ap[i], bv[j], oacc[i][j], 0, 0, 0);
    }
    __syncthreads();   // protect Ks/Vs/Ps before next staging
  }

  // epilogue: O / l -> attn_out (bf16) in [B,T,E] layout (E = h*64 + d)
  const int bb = bh >> 4, h = bh & 15;
#pragma unroll
  for (int i = 0; i < 2; ++i)
#pragma unroll
    for (int j = 0; j < 4; ++j)
#pragma unroll
      for (int r = 0; r < 4; ++r) {
        int t = qrow0 + i * 16 + quad * 4 + r;
        int d = j * 16 + l16;
        float v = oacc[i][j][r] / lst[i][r];
        Ao[((size_t)(bb * 2048 + t)) * 1024 + h * 64 + d] = f2bf(v);
      }
}

// ---------------------------------------------------------------------------
// Output projection: out[m][o] = sum_c att[m][c] * W_out[o][c]
// M=8192, N=1024, K=1024. A is bf16 (internal), W fp32 (converted in staging),
// OUTPUT IS FP32 (reference output dtype).
// ---------------------------------------------------------------------------
__global__ __launch_bounds__(256) void out_gemm(
    const u16* __restrict__ A, const float* __restrict__ W,
    float* __restrict__ O) {
  __shared__ u16 As[128 * LDSS];
  __shared__ u16 Bs[128 * LDSS];
  const int tid = threadIdx.x;
  const int lane = tid & 63;
  const int wv = tid >> 6;
  const int quad = lane >> 4;
  const int l16 = lane & 15;
  const int m0 = (wv >> 1) * 64;
  const int n0 = (wv & 1) * 64;
  const int rowA0 = blockIdx.y * 128;
  const int rowB0 = blockIdx.x * 128;

  f32x4 acc[4][4] = {};

  for (int kt = 0; kt < 1024; kt += 64) {
#pragma unroll
    for (int t = 0; t < 4; ++t) {
      int ch = tid + t * 256;
      int row = ch >> 3, cb = ch & 7;
      *(u16x8*)&As[row * LDSS + cb * 8] =
          *(const u16x8*)&A[(size_t)(rowA0 + row) * 1024 + kt + cb * 8];
      *(u16x8*)&Bs[row * LDSS + cb * 8] =
          cvt8(&W[(size_t)(rowB0 + row) * 1024 + kt + cb * 8]);
    }
    __syncthreads();
#pragma unroll
    for (int kk = 0; kk < 64; kk += 32) {
      bf16x8 af[4], bfr[4];
#pragma unroll
      for (int i = 0; i < 4; ++i)
        af[i] = ldfrag(&As[(m0 + i * 16 + l16) * LDSS + kk + quad * 8]);
#pragma unroll
      for (int j = 0; j < 4; ++j)
        bfr[j] = ldfrag(&Bs[(n0 + j * 16 + l16) * LDSS + kk + quad * 8]);
#pragma unroll
      for (int i = 0; i < 4; ++i)
#pragma unroll
        for (int j = 0; j < 4; ++j)
          acc[i][j] = __builtin_amdgcn_mfma_f32_16x16x32_bf16(af[i], bfr[j], acc[i][j], 0, 0, 0);
    }
    __syncthreads();
  }

#pragma unroll
  for (int i = 0; i < 4; ++i)
#pragma unroll
    for (int j = 0; j < 4; ++j)
#pragma unroll
      for (int r = 0; r < 4; ++r) {
        int m = rowA0 + m0 + i * 16 + quad * 4 + r;
        int o = rowB0 + n0 + j * 16 + l16;
        O[(size_t)m * 1024 + o] = acc[i][j][r];   // fp32 out
      }
}

extern "C" void kernel_launch(void* const* d_in, const int* in_sizes, int n_in,
                              void* d_out, int out_size, void* d_ws, size_t ws_size,
                              hipStream_t stream) {
  (void)in_sizes; (void)n_in; (void)out_size; (void)ws_size;
  const float* x    = (const float*)d_in[0];   // [4,2048,1024] fp32
  const float* Wqkv = (const float*)d_in[1];   // [3072,1024]  fp32
  const float* Wout = (const float*)d_in[2];   // [1024,1024]  fp32
  float* out = (float*)d_out;                  // [4,2048,1024] fp32
  u16* ws = (u16*)d_ws;

  const size_t SZ = (size_t)4 * 16 * 2048 * 64;  // 8,388,608 elems per tensor
  u16* Qw  = ws;            // [B,H,T,D] bf16, pre-scaled by 0.125
  u16* Kw  = ws + SZ;       // [B,H,T,D] bf16
  u16* Vtw = ws + 2 * SZ;   // [B,H,D,T] bf16 (transposed)
  u16* Ao  = ws + 3 * SZ;   // [B,T,E]   bf16

  qkv_gemm<<<dim3(24, 64), 256, 0, stream>>>(x, Wqkv, Qw, Kw, Vtw);
  attn_kernel<<<dim3(1024), 256, 0, stream>>>(Qw, Kw, Vtw, Ao);
  out_gemm<<<dim3(8, 64), 256, 0, stream>>>(Ao, Wout, out);
}

// Round 5
// 380.198 us; speedup vs baseline: 1.4257x; 1.4257x over previous
//
#include <hip/hip_runtime.h>

using u16 = unsigned short;
using u32 = unsigned int;
typedef __bf16 bf16;
typedef bf16 bf16x8 __attribute__((ext_vector_type(8)));
typedef u16 u16x8 __attribute__((ext_vector_type(8)));
typedef u16 u16x4 __attribute__((ext_vector_type(4)));
typedef float f32x4 __attribute__((ext_vector_type(4)));

// Problem constants: B=4, T=2048, E=1024, H=16, D=64
// Inputs fp32, output fp32 (reference dtypes). Internals bf16 (MFMA).
#define LDSS 72   // LDS row stride in bf16 elems (GEMM + attn P buffer)

__device__ __forceinline__ u16 f2bf(float f) {
  u32 u = __builtin_bit_cast(u32, f);
  u += 0x7FFFu + ((u >> 16) & 1u);   // round-to-nearest-even
  return (u16)(u >> 16);
}

__device__ __forceinline__ bf16x8 ldfrag(const u16* p) {
  return __builtin_bit_cast(bf16x8, *(const u16x8*)p);
}

__device__ __forceinline__ u16x8 cvt8(const float* p) {
  float4 a = ((const float4*)p)[0];
  float4 b = ((const float4*)p)[1];
  u16x8 o;
  o[0] = f2bf(a.x); o[1] = f2bf(a.y); o[2] = f2bf(a.z); o[3] = f2bf(a.w);
  o[4] = f2bf(b.x); o[5] = f2bf(b.y); o[6] = f2bf(b.z); o[7] = f2bf(b.w);
  return o;
}

// ---------------------------------------------------------------------------
// QKV projection: qkv[m][f] = sum_c x[m][c] * W_qkv[f][c]
// M=8192 (b,t), N=3072 (f), K=1024. fp32 sources converted in staging.
// Q is pre-scaled by 0.125*log2(e) (folds softmax scale + exp2 conversion).
// ---------------------------------------------------------------------------
__global__ __launch_bounds__(256) void qkv_gemm(
    const float* __restrict__ X, const float* __restrict__ W,
    u16* __restrict__ Qw, u16* __restrict__ Kw, u16* __restrict__ Vtw) {
  __shared__ u16 As[128 * LDSS];
  __shared__ u16 Bs[128 * LDSS];
  const int tid = threadIdx.x;
  const int lane = tid & 63;
  const int wv = tid >> 6;
  const int quad = lane >> 4;
  const int l16 = lane & 15;
  const int m0 = (wv >> 1) * 64;
  const int n0 = (wv & 1) * 64;
  const int rowA0 = blockIdx.y * 128;
  const int rowB0 = blockIdx.x * 128;

  f32x4 acc[4][4] = {};

  for (int kt = 0; kt < 1024; kt += 64) {
#pragma unroll
    for (int t = 0; t < 4; ++t) {
      int ch = tid + t * 256;
      int row = ch >> 3, cb = ch & 7;
      *(u16x8*)&As[row * LDSS + cb * 8] =
          cvt8(&X[(size_t)(rowA0 + row) * 1024 + kt + cb * 8]);
      *(u16x8*)&Bs[row * LDSS + cb * 8] =
          cvt8(&W[(size_t)(rowB0 + row) * 1024 + kt + cb * 8]);
    }
    __syncthreads();
#pragma unroll
    for (int kk = 0; kk < 64; kk += 32) {
      bf16x8 af[4], bfr[4];
#pragma unroll
      for (int i = 0; i < 4; ++i)
        af[i] = ldfrag(&As[(m0 + i * 16 + l16) * LDSS + kk + quad * 8]);
#pragma unroll
      for (int j = 0; j < 4; ++j)
        bfr[j] = ldfrag(&Bs[(n0 + j * 16 + l16) * LDSS + kk + quad * 8]);
#pragma unroll
      for (int i = 0; i < 4; ++i)
#pragma unroll
        for (int j = 0; j < 4; ++j)
          acc[i][j] = __builtin_amdgcn_mfma_f32_16x16x32_bf16(af[i], bfr[j], acc[i][j], 0, 0, 0);
    }
    __syncthreads();
  }

  const float QSCALE = 0.125f * 1.4426950408889634f;  // D^-0.5 * log2(e)
#pragma unroll
  for (int i = 0; i < 4; ++i)
#pragma unroll
    for (int j = 0; j < 4; ++j)
#pragma unroll
      for (int r = 0; r < 4; ++r) {
        int m = rowA0 + m0 + i * 16 + quad * 4 + r;   // C row
        int f = rowB0 + n0 + j * 16 + l16;            // C col
        float v = acc[i][j][r];
        int bb = m >> 11, t = m & 2047;
        int part = f >> 10, fi = f & 1023;
        int h = fi >> 6, d = fi & 63;
        if (part == 0) {
          Qw[((size_t)(bb * 16 + h) * 2048 + t) * 64 + d] = f2bf(v * QSCALE);
        } else if (part == 1) {
          Kw[((size_t)(bb * 16 + h) * 2048 + t) * 64 + d] = f2bf(v);
        } else {
          Vtw[((size_t)(bb * 16 + h) * 64 + d) * 2048 + t] = f2bf(v);
        }
      }
}

// ---------------------------------------------------------------------------
// Flash attention, transposed-S formulation. Block = (b,h) x 128-row Q tile;
// 4 waves, each owns 32 q-rows. S^T = K.Q^T so q = lane (C col) and softmax
// state m,l are per-lane scalars: 2 shuffles per reduction (xor 16,32).
// K and V A-frags load straight from global (k-contiguous layouts); the only
// LDS is a per-wave P^T buffer -> NO __syncthreads in the K-loop.
// Q pre-scaled by 0.125*log2e => raw exp2.
// Longest q-tiles dispatch first (load balance).
// ---------------------------------------------------------------------------
__global__ __launch_bounds__(256) void attn_kernel(
    const u16* __restrict__ Qw, const u16* __restrict__ Kw,
    const u16* __restrict__ Vtw, u16* __restrict__ Ao) {
  __shared__ u16 Ps[4][32 * LDSS];   // per-wave [q 32][key|d 64]
  const int tid = threadIdx.x;
  const int lane = tid & 63;
  const int wv = tid >> 6;
  const int quad = lane >> 4;
  const int l16 = lane & 15;
  const int qt = 15 - (blockIdx.x >> 6);   // longest first
  const int bh = blockIdx.x & 63;
  const u16* Qb = Qw + (size_t)bh * 2048 * 64;
  const u16* Kb = Kw + (size_t)bh * 2048 * 64;
  const u16* Vb = Vtw + (size_t)bh * 64 * 2048;
  const int qrow0 = qt * 128 + wv * 32;
  u16* pw = Ps[wv];

  // Q B-frags (n = q = l16, k = d = quad*8+j), held for the whole block
  bf16x8 qf[2][2];
#pragma unroll
  for (int i = 0; i < 2; ++i)
#pragma unroll
    for (int kk = 0; kk < 2; ++kk)
      qf[i][kk] = ldfrag(&Qb[(size_t)(qrow0 + i * 16 + l16) * 64 + kk * 32 + quad * 8]);

  f32x4 oacc[4][2] = {};          // O^T: [dblk][qblk]
  float mst[2] = {-INFINITY, -INFINITY};
  float lst[2] = {0.f, 0.f};

  const int nkt = 2 * qt + 2;
  for (int kt = 0; kt < nkt; ++kt) {
    const u16* Kt = Kb + (size_t)kt * 64 * 64;

    // S^T = K . Q^T  (64 keys x 32 q per wave): A = K frags from global
    f32x4 s[2][4] = {};            // [qblk][keyblk]
#pragma unroll
    for (int kk = 0; kk < 2; ++kk) {
      bf16x8 kf[4];
#pragma unroll
      for (int j = 0; j < 4; ++j)
        kf[j] = ldfrag(&Kt[(size_t)(j * 16 + l16) * 64 + kk * 32 + quad * 8]);
#pragma unroll
      for (int i = 0; i < 2; ++i)
#pragma unroll
        for (int j = 0; j < 4; ++j)
          s[i][j] = __builtin_amdgcn_mfma_f32_16x16x32_bf16(kf[j], qf[i][kk], s[i][j], 0, 0, 0);
    }

    // causal mask: key > q  (C-layout: row=key=quad*4+r, col=q=l16)
    if (kt * 64 + 63 > qrow0) {
#pragma unroll
      for (int i = 0; i < 2; ++i) {
        int q = qrow0 + i * 16 + l16;
#pragma unroll
        for (int j = 0; j < 4; ++j)
#pragma unroll
          for (int r = 0; r < 4; ++r)
            if (kt * 64 + j * 16 + quad * 4 + r > q) s[i][j][r] = -INFINITY;
      }
    }

    // online softmax: per-lane q-column; cross-quad combine via 2 shuffles
#pragma unroll
    for (int i = 0; i < 2; ++i) {
      float mx = -INFINITY;
#pragma unroll
      for (int j = 0; j < 4; ++j)
#pragma unroll
        for (int r = 0; r < 4; ++r) mx = fmaxf(mx, s[i][j][r]);
      mx = fmaxf(mx, __shfl_xor(mx, 16));
      mx = fmaxf(mx, __shfl_xor(mx, 32));
      float mnew = fmaxf(mst[i], mx);
      float alpha = exp2f(mst[i] - mnew);
      float rs = 0.f;
#pragma unroll
      for (int j = 0; j < 4; ++j) {
        u16x4 pk;
#pragma unroll
        for (int r = 0; r < 4; ++r) {
          float p = exp2f(s[i][j][r] - mnew);
          pk[r] = f2bf(p);
          rs += p;
        }
        // P^T row = q (i*16+l16), cols = 4 consecutive keys -> b64 write
        *(u16x4*)&pw[(i * 16 + l16) * LDSS + j * 16 + quad * 4] = pk;
      }
      rs += __shfl_xor(rs, 16);
      rs += __shfl_xor(rs, 32);
      lst[i] = lst[i] * alpha + rs;
      mst[i] = mnew;
#pragma unroll
      for (int d = 0; d < 4; ++d) oacc[d][i] *= alpha;
    }

    // O^T += V^T . P^T   (A = V^T frags from global, B = P^T from own LDS)
#pragma unroll
    for (int kk = 0; kk < 2; ++kk) {
      bf16x8 vf[4], pf[2];
#pragma unroll
      for (int d = 0; d < 4; ++d)
        vf[d] = ldfrag(&Vb[(size_t)(d * 16 + l16) * 2048 + kt * 64 + kk * 32 + quad * 8]);
#pragma unroll
      for (int i = 0; i < 2; ++i)
        pf[i] = ldfrag(&pw[(i * 16 + l16) * LDSS + kk * 32 + quad * 8]);
#pragma unroll
      for (int d = 0; d < 4; ++d)
#pragma unroll
        for (int i = 0; i < 2; ++i)
          oacc[d][i] = __builtin_amdgcn_mfma_f32_16x16x32_bf16(vf[d], pf[i], oacc[d][i], 0, 0, 0);
    }
  }

  // epilogue: O^T / l -> LDS transpose -> coalesced bf16 store to Ao [B,T,E]
  const int bb = bh >> 4, h = bh & 15;
#pragma unroll
  for (int i = 0; i < 2; ++i) {
    float inv = 1.f / lst[i];
#pragma unroll
    for (int d = 0; d < 4; ++d) {
      u16x4 ok;
#pragma unroll
      for (int r = 0; r < 4; ++r) ok[r] = f2bf(oacc[d][i][r] * inv);
      *(u16x4*)&pw[(i * 16 + l16) * LDSS + d * 16 + quad * 4] = ok;
    }
  }
  __builtin_amdgcn_s_waitcnt(0);   // lgkm drain (same-wave write->read)
  const int row = lane >> 1, half = lane & 1;
  const int t = qrow0 + row;
#pragma unroll
  for (int c = 0; c < 4; ++c) {
    u16x8 v = *(u16x8*)&pw[row * LDSS + half * 32 + c * 8];
    *(u16x8*)&Ao[((size_t)(bb * 2048 + t)) * 1024 + h * 64 + half * 32 + c * 8] = v;
  }
}

// ---------------------------------------------------------------------------
// Output projection: out[m][o] = sum_c att[m][c] * W_out[o][c]
// M=8192, N=1024, K=1024. A bf16, W fp32 (converted in staging), OUT FP32.
// ---------------------------------------------------------------------------
__global__ __launch_bounds__(256) void out_gemm(
    const u16* __restrict__ A, const float* __restrict__ W,
    float* __restrict__ O) {
  __shared__ u16 As[128 * LDSS];
  __shared__ u16 Bs[128 * LDSS];
  const int tid = threadIdx.x;
  const int lane = tid & 63;
  const int wv = tid >> 6;
  const int quad = lane >> 4;
  const int l16 = lane & 15;
  const int m0 = (wv >> 1) * 64;
  const int n0 = (wv & 1) * 64;
  const int rowA0 = blockIdx.y * 128;
  const int rowB0 = blockIdx.x * 128;

  f32x4 acc[4][4] = {};

  for (int kt = 0; kt < 1024; kt += 64) {
#pragma unroll
    for (int t = 0; t < 4; ++t) {
      int ch = tid + t * 256;
      int row = ch >> 3, cb = ch & 7;
      *(u16x8*)&As[row * LDSS + cb * 8] =
          *(const u16x8*)&A[(size_t)(rowA0 + row) * 1024 + kt + cb * 8];
      *(u16x8*)&Bs[row * LDSS + cb * 8] =
          cvt8(&W[(size_t)(rowB0 + row) * 1024 + kt + cb * 8]);
    }
    __syncthreads();
#pragma unroll
    for (int kk = 0; kk < 64; kk += 32) {
      bf16x8 af[4], bfr[4];
#pragma unroll
      for (int i = 0; i < 4; ++i)
        af[i] = ldfrag(&As[(m0 + i * 16 + l16) * LDSS + kk + quad * 8]);
#pragma unroll
      for (int j = 0; j < 4; ++j)
        bfr[j] = ldfrag(&Bs[(n0 + j * 16 + l16) * LDSS + kk + quad * 8]);
#pragma unroll
      for (int i = 0; i < 4; ++i)
#pragma unroll
        for (int j = 0; j < 4; ++j)
          acc[i][j] = __builtin_amdgcn_mfma_f32_16x16x32_bf16(af[i], bfr[j], acc[i][j], 0, 0, 0);
    }
    __syncthreads();
  }

#pragma unroll
  for (int i = 0; i < 4; ++i)
#pragma unroll
    for (int j = 0; j < 4; ++j)
#pragma unroll
      for (int r = 0; r < 4; ++r) {
        int m = rowA0 + m0 + i * 16 + quad * 4 + r;
        int o = rowB0 + n0 + j * 16 + l16;
        O[(size_t)m * 1024 + o] = acc[i][j][r];   // fp32 out
      }
}

extern "C" void kernel_launch(void* const* d_in, const int* in_sizes, int n_in,
                              void* d_out, int out_size, void* d_ws, size_t ws_size,
                              hipStream_t stream) {
  (void)in_sizes; (void)n_in; (void)out_size; (void)ws_size;
  const float* x    = (const float*)d_in[0];   // [4,2048,1024] fp32
  const float* Wqkv = (const float*)d_in[1];   // [3072,1024]  fp32
  const float* Wout = (const float*)d_in[2];   // [1024,1024]  fp32
  float* out = (float*)d_out;                  // [4,2048,1024] fp32
  u16* ws = (u16*)d_ws;

  const size_t SZ = (size_t)4 * 16 * 2048 * 64;  // 8,388,608 elems per tensor
  u16* Qw  = ws;            // [B,H,T,D] bf16, pre-scaled by 0.125*log2e
  u16* Kw  = ws + SZ;       // [B,H,T,D] bf16
  u16* Vtw = ws + 2 * SZ;   // [B,H,D,T] bf16 (transposed)
  u16* Ao  = ws + 3 * SZ;   // [B,T,E]   bf16

  qkv_gemm<<<dim3(24, 64), 256, 0, stream>>>(x, Wqkv, Qw, Kw, Vtw);
  attn_kernel<<<dim3(1024), 256, 0, stream>>>(Qw, Kw, Vtw, Ao);
  out_gemm<<<dim3(8, 64), 256, 0, stream>>>(Ao, Wout, out);
}

// Round 6
// 356.009 us; speedup vs baseline: 1.5225x; 1.0679x over previous
//
#include <hip/hip_runtime.h>

using u16 = unsigned short;
using u32 = unsigned int;
typedef __bf16 bf16;
typedef bf16 bf16x8 __attribute__((ext_vector_type(8)));
typedef u16 u16x8 __attribute__((ext_vector_type(8)));
typedef u16 u16x4 __attribute__((ext_vector_type(4)));
typedef float f32x4 __attribute__((ext_vector_type(4)));

// Problem constants: B=4, T=2048, E=1024, H=16, D=64
// Inputs fp32, output fp32. Internals bf16 (MFMA).
#define LDSS 72   // padded stride, attn P buffer only (GEMM tiles are unpadded for global_load_lds)

__device__ __forceinline__ u16 f2bf(float f) {
  u32 u = __builtin_bit_cast(u32, f);
  u += 0x7FFFu + ((u >> 16) & 1u);   // round-to-nearest-even
  return (u16)(u >> 16);
}

__device__ __forceinline__ bf16x8 ldfrag(const u16* p) {
  return __builtin_bit_cast(bf16x8, *(const u16x8*)p);
}

__device__ __forceinline__ u16x8 cvt8(const float* p) {
  float4 a = ((const float4*)p)[0];
  float4 b = ((const float4*)p)[1];
  u16x8 o;
  o[0] = f2bf(a.x); o[1] = f2bf(a.y); o[2] = f2bf(a.z); o[3] = f2bf(a.w);
  o[4] = f2bf(b.x); o[5] = f2bf(b.y); o[6] = f2bf(b.z); o[7] = f2bf(b.w);
  return o;
}

// async global->LDS, 16 B per lane; LDS dest = wave-uniform base + lane*16
__device__ __forceinline__ void gll16(const u16* g, u16* l) {
  __builtin_amdgcn_global_load_lds(
      (const __attribute__((address_space(1))) u32*)g,
      (__attribute__((address_space(3))) u32*)l, 16, 0, 0);
}

// ---------------------------------------------------------------------------
// fp32 -> bf16 convert (one-time; feeds global_load_lds GEMMs)
// ---------------------------------------------------------------------------
__global__ __launch_bounds__(256) void cvt_bf16(
    const float* __restrict__ src, u16* __restrict__ dst, int n8) {
  int i = blockIdx.x * 256 + threadIdx.x;
  const int stride = gridDim.x * 256;
  for (; i < n8; i += stride)
    ((u16x8*)dst)[i] = cvt8(&src[(size_t)i * 8]);
}

// ---------------------------------------------------------------------------
// QKV projection (m97-style): qkv[m][f] = sum_c x[m][c] * W_qkv[f][c]
// M=8192, N=3072, K=1024, bf16 sources, global_load_lds staging, BK=64.
// Epilogue scatters Q (pre-scaled 0.125*log2e) / K -> [B,H,T,D], V -> [B,H,D,T].
// ---------------------------------------------------------------------------
__global__ __launch_bounds__(256) void qkv_gemm(
    const u16* __restrict__ X, const u16* __restrict__ W,
    u16* __restrict__ Qw, u16* __restrict__ Kw, u16* __restrict__ Vtw) {
  __shared__ u16 As[128 * 64];   // unpadded: required by global_load_lds layout
  __shared__ u16 Bs[128 * 64];
  const int tid = threadIdx.x;
  const int lane = tid & 63;
  const int wv = tid >> 6;
  const int quad = lane >> 4;
  const int l16 = lane & 15;
  const int m0 = (wv >> 1) * 64;
  const int n0 = (wv & 1) * 64;
  const int rowA0 = blockIdx.y * 128;
  const int rowB0 = blockIdx.x * 128;

  f32x4 acc[4][4] = {};

  for (int kt = 0; kt < 1024; kt += 64) {
#pragma unroll
    for (int t = 0; t < 4; ++t) {
      int base = t * 256 + wv * 64;        // wave-uniform chunk base
      int idx = base + lane;               // per-lane chunk (16 B)
      int row = idx >> 3, c = (idx & 7) * 8;
      gll16(&X[(size_t)(rowA0 + row) * 1024 + kt + c], &As[base * 8]);
      gll16(&W[(size_t)(rowB0 + row) * 1024 + kt + c], &Bs[base * 8]);
    }
    __syncthreads();
#pragma unroll
    for (int kk = 0; kk < 64; kk += 32) {
      bf16x8 af[4], bfr[4];
#pragma unroll
      for (int i = 0; i < 4; ++i)
        af[i] = ldfrag(&As[(m0 + i * 16 + l16) * 64 + kk + quad * 8]);
#pragma unroll
      for (int j = 0; j < 4; ++j)
        bfr[j] = ldfrag(&Bs[(n0 + j * 16 + l16) * 64 + kk + quad * 8]);
#pragma unroll
      for (int i = 0; i < 4; ++i)
#pragma unroll
        for (int j = 0; j < 4; ++j)
          acc[i][j] = __builtin_amdgcn_mfma_f32_16x16x32_bf16(af[i], bfr[j], acc[i][j], 0, 0, 0);
    }
    __syncthreads();
  }

  const float QSCALE = 0.125f * 1.4426950408889634f;  // D^-0.5 * log2(e)
#pragma unroll
  for (int i = 0; i < 4; ++i)
#pragma unroll
    for (int j = 0; j < 4; ++j)
#pragma unroll
      for (int r = 0; r < 4; ++r) {
        int m = rowA0 + m0 + i * 16 + quad * 4 + r;   // C row
        int f = rowB0 + n0 + j * 16 + l16;            // C col
        float v = acc[i][j][r];
        int bb = m >> 11, t = m & 2047;
        int part = f >> 10, fi = f & 1023;
        int h = fi >> 6, d = fi & 63;
        if (part == 0) {
          Qw[((size_t)(bb * 16 + h) * 2048 + t) * 64 + d] = f2bf(v * QSCALE);
        } else if (part == 1) {
          Kw[((size_t)(bb * 16 + h) * 2048 + t) * 64 + d] = f2bf(v);
        } else {
          Vtw[((size_t)(bb * 16 + h) * 64 + d) * 2048 + t] = f2bf(v);
        }
      }
}

// ---------------------------------------------------------------------------
// Flash attention, transposed-S formulation (unchanged from R4 win).
// ---------------------------------------------------------------------------
__global__ __launch_bounds__(256) void attn_kernel(
    const u16* __restrict__ Qw, const u16* __restrict__ Kw,
    const u16* __restrict__ Vtw, u16* __restrict__ Ao) {
  __shared__ u16 Ps[4][32 * LDSS];   // per-wave [q 32][key|d 64]
  const int tid = threadIdx.x;
  const int lane = tid & 63;
  const int wv = tid >> 6;
  const int quad = lane >> 4;
  const int l16 = lane & 15;
  const int qt = 15 - (blockIdx.x >> 6);   // longest first
  const int bh = blockIdx.x & 63;
  const u16* Qb = Qw + (size_t)bh * 2048 * 64;
  const u16* Kb = Kw + (size_t)bh * 2048 * 64;
  const u16* Vb = Vtw + (size_t)bh * 64 * 2048;
  const int qrow0 = qt * 128 + wv * 32;
  u16* pw = Ps[wv];

  bf16x8 qf[2][2];
#pragma unroll
  for (int i = 0; i < 2; ++i)
#pragma unroll
    for (int kk = 0; kk < 2; ++kk)
      qf[i][kk] = ldfrag(&Qb[(size_t)(qrow0 + i * 16 + l16) * 64 + kk * 32 + quad * 8]);

  f32x4 oacc[4][2] = {};          // O^T: [dblk][qblk]
  float mst[2] = {-INFINITY, -INFINITY};
  float lst[2] = {0.f, 0.f};

  const int nkt = 2 * qt + 2;
  for (int kt = 0; kt < nkt; ++kt) {
    const u16* Kt = Kb + (size_t)kt * 64 * 64;

    f32x4 s[2][4] = {};            // [qblk][keyblk]
#pragma unroll
    for (int kk = 0; kk < 2; ++kk) {
      bf16x8 kf[4];
#pragma unroll
      for (int j = 0; j < 4; ++j)
        kf[j] = ldfrag(&Kt[(size_t)(j * 16 + l16) * 64 + kk * 32 + quad * 8]);
#pragma unroll
      for (int i = 0; i < 2; ++i)
#pragma unroll
        for (int j = 0; j < 4; ++j)
          s[i][j] = __builtin_amdgcn_mfma_f32_16x16x32_bf16(kf[j], qf[i][kk], s[i][j], 0, 0, 0);
    }

    if (kt * 64 + 63 > qrow0) {
#pragma unroll
      for (int i = 0; i < 2; ++i) {
        int q = qrow0 + i * 16 + l16;
#pragma unroll
        for (int j = 0; j < 4; ++j)
#pragma unroll
          for (int r = 0; r < 4; ++r)
            if (kt * 64 + j * 16 + quad * 4 + r > q) s[i][j][r] = -INFINITY;
      }
    }

#pragma unroll
    for (int i = 0; i < 2; ++i) {
      float mx = -INFINITY;
#pragma unroll
      for (int j = 0; j < 4; ++j)
#pragma unroll
        for (int r = 0; r < 4; ++r) mx = fmaxf(mx, s[i][j][r]);
      mx = fmaxf(mx, __shfl_xor(mx, 16));
      mx = fmaxf(mx, __shfl_xor(mx, 32));
      float mnew = fmaxf(mst[i], mx);
      float alpha = exp2f(mst[i] - mnew);
      float rs = 0.f;
#pragma unroll
      for (int j = 0; j < 4; ++j) {
        u16x4 pk;
#pragma unroll
        for (int r = 0; r < 4; ++r) {
          float p = exp2f(s[i][j][r] - mnew);
          pk[r] = f2bf(p);
          rs += p;
        }
        *(u16x4*)&pw[(i * 16 + l16) * LDSS + j * 16 + quad * 4] = pk;
      }
      rs += __shfl_xor(rs, 16);
      rs += __shfl_xor(rs, 32);
      lst[i] = lst[i] * alpha + rs;
      mst[i] = mnew;
#pragma unroll
      for (int d = 0; d < 4; ++d) oacc[d][i] *= alpha;
    }

#pragma unroll
    for (int kk = 0; kk < 2; ++kk) {
      bf16x8 vf[4], pf[2];
#pragma unroll
      for (int d = 0; d < 4; ++d)
        vf[d] = ldfrag(&Vb[(size_t)(d * 16 + l16) * 2048 + kt * 64 + kk * 32 + quad * 8]);
#pragma unroll
      for (int i = 0; i < 2; ++i)
        pf[i] = ldfrag(&pw[(i * 16 + l16) * LDSS + kk * 32 + quad * 8]);
#pragma unroll
      for (int d = 0; d < 4; ++d)
#pragma unroll
        for (int i = 0; i < 2; ++i)
          oacc[d][i] = __builtin_amdgcn_mfma_f32_16x16x32_bf16(vf[d], pf[i], oacc[d][i], 0, 0, 0);
    }
  }

  const int bb = bh >> 4, h = bh & 15;
#pragma unroll
  for (int i = 0; i < 2; ++i) {
    float inv = 1.f / lst[i];
#pragma unroll
    for (int d = 0; d < 4; ++d) {
      u16x4 ok;
#pragma unroll
      for (int r = 0; r < 4; ++r) ok[r] = f2bf(oacc[d][i][r] * inv);
      *(u16x4*)&pw[(i * 16 + l16) * LDSS + d * 16 + quad * 4] = ok;
    }
  }
  __builtin_amdgcn_s_waitcnt(0);   // lgkm drain (same-wave write->read)
  const int row = lane >> 1, half = lane & 1;
  const int t = qrow0 + row;
#pragma unroll
  for (int c = 0; c < 4; ++c) {
    u16x8 v = *(u16x8*)&pw[row * LDSS + half * 32 + c * 8];
    *(u16x8*)&Ao[((size_t)(bb * 2048 + t)) * 1024 + h * 64 + half * 32 + c * 8] = v;
  }
}

// ---------------------------------------------------------------------------
// Output projection (m97-style): out[m][o] = sum_c att[m][c] * W_out[o][c]
// M=8192, N=1024, K=1024, bf16 sources, global_load_lds staging, FP32 out.
// ---------------------------------------------------------------------------
__global__ __launch_bounds__(256) void out_gemm(
    const u16* __restrict__ A, const u16* __restrict__ W,
    float* __restrict__ O) {
  __shared__ u16 As[128 * 64];
  __shared__ u16 Bs[128 * 64];
  const int tid = threadIdx.x;
  const int lane = tid & 63;
  const int wv = tid >> 6;
  const int quad = lane >> 4;
  const int l16 = lane & 15;
  const int m0 = (wv >> 1) * 64;
  const int n0 = (wv & 1) * 64;
  const int rowA0 = blockIdx.y * 128;
  const int rowB0 = blockIdx.x * 128;

  f32x4 acc[4][4] = {};

  for (int kt = 0; kt < 1024; kt += 64) {
#pragma unroll
    for (int t = 0; t < 4; ++t) {
      int base = t * 256 + wv * 64;
      int idx = base + lane;
      int row = idx >> 3, c = (idx & 7) * 8;
      gll16(&A[(size_t)(rowA0 + row) * 1024 + kt + c], &As[base * 8]);
      gll16(&W[(size_t)(rowB0 + row) * 1024 + kt + c], &Bs[base * 8]);
    }
    __syncthreads();
#pragma unroll
    for (int kk = 0; kk < 64; kk += 32) {
      bf16x8 af[4], bfr[4];
#pragma unroll
      for (int i = 0; i < 4; ++i)
        af[i] = ldfrag(&As[(m0 + i * 16 + l16) * 64 + kk + quad * 8]);
#pragma unroll
      for (int j = 0; j < 4; ++j)
        bfr[j] = ldfrag(&Bs[(n0 + j * 16 + l16) * 64 + kk + quad * 8]);
#pragma unroll
      for (int i = 0; i < 4; ++i)
#pragma unroll
        for (int j = 0; j < 4; ++j)
          acc[i][j] = __builtin_amdgcn_mfma_f32_16x16x32_bf16(af[i], bfr[j], acc[i][j], 0, 0, 0);
    }
    __syncthreads();
  }

#pragma unroll
  for (int i = 0; i < 4; ++i)
#pragma unroll
    for (int j = 0; j < 4; ++j)
#pragma unroll
      for (int r = 0; r < 4; ++r) {
        int m = rowA0 + m0 + i * 16 + quad * 4 + r;
        int o = rowB0 + n0 + j * 16 + l16;
        O[(size_t)m * 1024 + o] = acc[i][j][r];   // fp32 out
      }
}

extern "C" void kernel_launch(void* const* d_in, const int* in_sizes, int n_in,
                              void* d_out, int out_size, void* d_ws, size_t ws_size,
                              hipStream_t stream) {
  (void)in_sizes; (void)n_in; (void)out_size; (void)ws_size;
  const float* x    = (const float*)d_in[0];   // [4,2048,1024] fp32
  const float* Wqkv = (const float*)d_in[1];   // [3072,1024]  fp32
  const float* Wout = (const float*)d_in[2];   // [1024,1024]  fp32
  float* out = (float*)d_out;                  // [4,2048,1024] fp32
  u16* ws = (u16*)d_ws;

  const size_t NX   = (size_t)4 * 2048 * 1024;  // 8,388,608
  const size_t NQKV = (size_t)3072 * 1024;      // 3,145,728
  const size_t NOUT = (size_t)1024 * 1024;      // 1,048,576
  const size_t SZ   = NX;

  u16* Xc    = ws;               // bf16 inputs
  u16* Wqkvc = Xc + NX;
  u16* Woutc = Wqkvc + NQKV;
  u16* Qw    = Woutc + NOUT;     // [B,H,T,D] bf16, pre-scaled 0.125*log2e
  u16* Kw    = Qw + SZ;          // [B,H,T,D] bf16
  u16* Vtw   = Kw + SZ;          // [B,H,D,T] bf16 (transposed)
  u16* Ao    = Vtw + SZ;         // [B,T,E]   bf16

  cvt_bf16<<<dim3(1024), 256, 0, stream>>>(x, Xc, (int)(NX / 8));
  cvt_bf16<<<dim3(384), 256, 0, stream>>>(Wqkv, Wqkvc, (int)(NQKV / 8));
  cvt_bf16<<<dim3(128), 256, 0, stream>>>(Wout, Woutc, (int)(NOUT / 8));

  qkv_gemm<<<dim3(24, 64), 256, 0, stream>>>(Xc, Wqkvc, Qw, Kw, Vtw);
  attn_kernel<<<dim3(1024), 256, 0, stream>>>(Qw, Kw, Vtw, Ao);
  out_gemm<<<dim3(8, 64), 256, 0, stream>>>(Ao, Woutc, out);
}

// Round 7
// 350.172 us; speedup vs baseline: 1.5479x; 1.0167x over previous
//
#include <hip/hip_runtime.h>

using u16 = unsigned short;
using u32 = unsigned int;
typedef __bf16 bf16;
typedef bf16 bf16x8 __attribute__((ext_vector_type(8)));
typedef u16 u16x8 __attribute__((ext_vector_type(8)));
typedef u16 u16x4 __attribute__((ext_vector_type(4)));
typedef float f32x4 __attribute__((ext_vector_type(4)));

// Problem constants: B=4, T=2048, E=1024, H=16, D=64
// Inputs fp32, output fp32. Internals bf16 (MFMA).
#define LDSS 72   // padded stride, attn P buffer only (GEMM tiles are unpadded for global_load_lds)

__device__ __forceinline__ u16 f2bf(float f) {
  u32 u = __builtin_bit_cast(u32, f);
  u += 0x7FFFu + ((u >> 16) & 1u);   // round-to-nearest-even
  return (u16)(u >> 16);
}

__device__ __forceinline__ bf16x8 ldfrag(const u16* p) {
  return __builtin_bit_cast(bf16x8, *(const u16x8*)p);
}

__device__ __forceinline__ u16x8 cvt8(const float* p) {
  float4 a = ((const float4*)p)[0];
  float4 b = ((const float4*)p)[1];
  u16x8 o;
  o[0] = f2bf(a.x); o[1] = f2bf(a.y); o[2] = f2bf(a.z); o[3] = f2bf(a.w);
  o[4] = f2bf(b.x); o[5] = f2bf(b.y); o[6] = f2bf(b.z); o[7] = f2bf(b.w);
  return o;
}

// async global->LDS, 16 B per lane; LDS dest = wave-uniform base + lane*16
__device__ __forceinline__ void gll16(const u16* g, u16* l) {
  __builtin_amdgcn_global_load_lds(
      (const __attribute__((address_space(1))) u32*)g,
      (__attribute__((address_space(3))) u32*)l, 16, 0, 0);
}

// ---------------------------------------------------------------------------
// fp32 -> bf16 convert (one-time; feeds global_load_lds GEMMs)
// ---------------------------------------------------------------------------
__global__ __launch_bounds__(256) void cvt_bf16(
    const float* __restrict__ src, u16* __restrict__ dst, int n8) {
  int i = blockIdx.x * 256 + threadIdx.x;
  const int stride = gridDim.x * 256;
  for (; i < n8; i += stride)
    ((u16x8*)dst)[i] = cvt8(&src[(size_t)i * 8]);
}

// ---------------------------------------------------------------------------
// QKV projection (m97-style): qkv[m][f] = sum_c x[m][c] * W_qkv[f][c]
// M=8192, N=3072, K=1024, bf16 sources, global_load_lds staging, BK=64.
// ---------------------------------------------------------------------------
__global__ __launch_bounds__(256) void qkv_gemm(
    const u16* __restrict__ X, const u16* __restrict__ W,
    u16* __restrict__ Qw, u16* __restrict__ Kw, u16* __restrict__ Vtw) {
  __shared__ u16 As[128 * 64];   // unpadded: required by global_load_lds layout
  __shared__ u16 Bs[128 * 64];
  const int tid = threadIdx.x;
  const int lane = tid & 63;
  const int wv = tid >> 6;
  const int quad = lane >> 4;
  const int l16 = lane & 15;
  const int m0 = (wv >> 1) * 64;
  const int n0 = (wv & 1) * 64;
  const int rowA0 = blockIdx.y * 128;
  const int rowB0 = blockIdx.x * 128;

  f32x4 acc[4][4] = {};

  for (int kt = 0; kt < 1024; kt += 64) {
#pragma unroll
    for (int t = 0; t < 4; ++t) {
      int base = t * 256 + wv * 64;        // wave-uniform chunk base
      int idx = base + lane;               // per-lane chunk (16 B)
      int row = idx >> 3, c = (idx & 7) * 8;
      gll16(&X[(size_t)(rowA0 + row) * 1024 + kt + c], &As[base * 8]);
      gll16(&W[(size_t)(rowB0 + row) * 1024 + kt + c], &Bs[base * 8]);
    }
    __syncthreads();
#pragma unroll
    for (int kk = 0; kk < 64; kk += 32) {
      bf16x8 af[4], bfr[4];
#pragma unroll
      for (int i = 0; i < 4; ++i)
        af[i] = ldfrag(&As[(m0 + i * 16 + l16) * 64 + kk + quad * 8]);
#pragma unroll
      for (int j = 0; j < 4; ++j)
        bfr[j] = ldfrag(&Bs[(n0 + j * 16 + l16) * 64 + kk + quad * 8]);
#pragma unroll
      for (int i = 0; i < 4; ++i)
#pragma unroll
        for (int j = 0; j < 4; ++j)
          acc[i][j] = __builtin_amdgcn_mfma_f32_16x16x32_bf16(af[i], bfr[j], acc[i][j], 0, 0, 0);
    }
    __syncthreads();
  }

  const float QSCALE = 0.125f * 1.4426950408889634f;  // D^-0.5 * log2(e)
#pragma unroll
  for (int i = 0; i < 4; ++i)
#pragma unroll
    for (int j = 0; j < 4; ++j)
#pragma unroll
      for (int r = 0; r < 4; ++r) {
        int m = rowA0 + m0 + i * 16 + quad * 4 + r;   // C row
        int f = rowB0 + n0 + j * 16 + l16;            // C col
        float v = acc[i][j][r];
        int bb = m >> 11, t = m & 2047;
        int part = f >> 10, fi = f & 1023;
        int h = fi >> 6, d = fi & 63;
        if (part == 0) {
          Qw[((size_t)(bb * 16 + h) * 2048 + t) * 64 + d] = f2bf(v * QSCALE);
        } else if (part == 1) {
          Kw[((size_t)(bb * 16 + h) * 2048 + t) * 64 + d] = f2bf(v);
        } else {
          Vtw[((size_t)(bb * 16 + h) * 64 + d) * 2048 + t] = f2bf(v);
        }
      }
}

// ---------------------------------------------------------------------------
// Flash attention, transposed-S, ONE WAVE PER BLOCK (64 threads).
// Block = (b,h) x 32-q-row stripe -> 4096 fine-grained blocks (16/CU),
// longest stripes dispatched first. No __syncthreads anywhere; P^T buffer is
// private to the wave. Q pre-scaled by 0.125*log2e => raw exp2.
// ---------------------------------------------------------------------------
__global__ __launch_bounds__(64) void attn_kernel(
    const u16* __restrict__ Qw, const u16* __restrict__ Kw,
    const u16* __restrict__ Vtw, u16* __restrict__ Ao) {
  __shared__ u16 pw[32 * LDSS];      // per-wave [q 32][key|d 64]
  const int lane = threadIdx.x & 63;
  const int quad = lane >> 4;
  const int l16 = lane & 15;
  const int s = 63 - (blockIdx.x >> 6);   // q-stripe, longest first
  const int bh = blockIdx.x & 63;
  const u16* Qb = Qw + (size_t)bh * 2048 * 64;
  const u16* Kb = Kw + (size_t)bh * 2048 * 64;
  const u16* Vb = Vtw + (size_t)bh * 64 * 2048;
  const int qrow0 = s * 32;

  // Q B-frags (n = q = l16, k = d = quad*8+j), held for the whole block
  bf16x8 qf[2][2];
#pragma unroll
  for (int i = 0; i < 2; ++i)
#pragma unroll
    for (int kk = 0; kk < 2; ++kk)
      qf[i][kk] = ldfrag(&Qb[(size_t)(qrow0 + i * 16 + l16) * 64 + kk * 32 + quad * 8]);

  f32x4 oacc[4][2] = {};          // O^T: [dblk][qblk]
  float mst[2] = {-INFINITY, -INFINITY};
  float lst[2] = {0.f, 0.f};

  const int nkt = (s >> 1) + 1;   // tiles covering keys <= qrow0+31
  for (int kt = 0; kt < nkt; ++kt) {
    const u16* Kt = Kb + (size_t)kt * 64 * 64;

    // S^T = K . Q^T  (64 keys x 32 q): A = K frags from global
    f32x4 sv[2][4] = {};           // [qblk][keyblk]
#pragma unroll
    for (int kk = 0; kk < 2; ++kk) {
      bf16x8 kf[4];
#pragma unroll
      for (int j = 0; j < 4; ++j)
        kf[j] = ldfrag(&Kt[(size_t)(j * 16 + l16) * 64 + kk * 32 + quad * 8]);
#pragma unroll
      for (int i = 0; i < 2; ++i)
#pragma unroll
        for (int j = 0; j < 4; ++j)
          sv[i][j] = __builtin_amdgcn_mfma_f32_16x16x32_bf16(kf[j], qf[i][kk], sv[i][j], 0, 0, 0);
    }

    // causal mask: key > q  (C-layout: row=key=quad*4+r, col=q=l16)
    if (kt * 64 + 63 > qrow0) {
#pragma unroll
      for (int i = 0; i < 2; ++i) {
        int q = qrow0 + i * 16 + l16;
#pragma unroll
        for (int j = 0; j < 4; ++j)
#pragma unroll
          for (int r = 0; r < 4; ++r)
            if (kt * 64 + j * 16 + quad * 4 + r > q) sv[i][j][r] = -INFINITY;
      }
    }

    // online softmax: per-lane q-column; cross-quad combine via 2 shuffles
#pragma unroll
    for (int i = 0; i < 2; ++i) {
      float mx = -INFINITY;
#pragma unroll
      for (int j = 0; j < 4; ++j)
#pragma unroll
        for (int r = 0; r < 4; ++r) mx = fmaxf(mx, sv[i][j][r]);
      mx = fmaxf(mx, __shfl_xor(mx, 16));
      mx = fmaxf(mx, __shfl_xor(mx, 32));
      float mnew = fmaxf(mst[i], mx);
      float alpha = exp2f(mst[i] - mnew);
      float rs = 0.f;
#pragma unroll
      for (int j = 0; j < 4; ++j) {
        u16x4 pk;
#pragma unroll
        for (int r = 0; r < 4; ++r) {
          float p = exp2f(sv[i][j][r] - mnew);
          pk[r] = f2bf(p);
          rs += p;
        }
        // P^T row = q (i*16+l16), cols = 4 consecutive keys -> b64 write
        *(u16x4*)&pw[(i * 16 + l16) * LDSS + j * 16 + quad * 4] = pk;
      }
      rs += __shfl_xor(rs, 16);
      rs += __shfl_xor(rs, 32);
      lst[i] = lst[i] * alpha + rs;
      mst[i] = mnew;
#pragma unroll
      for (int d = 0; d < 4; ++d) oacc[d][i] *= alpha;
    }

    // O^T += V^T . P^T   (A = V^T frags from global, B = P^T from own LDS)
#pragma unroll
    for (int kk = 0; kk < 2; ++kk) {
      bf16x8 vf[4], pf[2];
#pragma unroll
      for (int d = 0; d < 4; ++d)
        vf[d] = ldfrag(&Vb[(size_t)(d * 16 + l16) * 2048 + kt * 64 + kk * 32 + quad * 8]);
#pragma unroll
      for (int i = 0; i < 2; ++i)
        pf[i] = ldfrag(&pw[(i * 16 + l16) * LDSS + kk * 32 + quad * 8]);
#pragma unroll
      for (int d = 0; d < 4; ++d)
#pragma unroll
        for (int i = 0; i < 2; ++i)
          oacc[d][i] = __builtin_amdgcn_mfma_f32_16x16x32_bf16(vf[d], pf[i], oacc[d][i], 0, 0, 0);
    }
  }

  // epilogue: O^T / l -> LDS transpose -> coalesced bf16 store to Ao [B,T,E]
  const int bb = bh >> 4, h = bh & 15;
#pragma unroll
  for (int i = 0; i < 2; ++i) {
    float inv = 1.f / lst[i];
#pragma unroll
    for (int d = 0; d < 4; ++d) {
      u16x4 ok;
#pragma unroll
      for (int r = 0; r < 4; ++r) ok[r] = f2bf(oacc[d][i][r] * inv);
      *(u16x4*)&pw[(i * 16 + l16) * LDSS + d * 16 + quad * 4] = ok;
    }
  }
  __builtin_amdgcn_s_waitcnt(0);   // lgkm drain (same-wave write->read)
  const int row = lane >> 1, half = lane & 1;
  const int t = qrow0 + row;
#pragma unroll
  for (int c = 0; c < 4; ++c) {
    u16x8 v = *(u16x8*)&pw[row * LDSS + half * 32 + c * 8];
    *(u16x8*)&Ao[((size_t)(bb * 2048 + t)) * 1024 + h * 64 + half * 32 + c * 8] = v;
  }
}

// ---------------------------------------------------------------------------
// Output projection (m97-style): out[m][o] = sum_c att[m][c] * W_out[o][c]
// M=8192, N=1024, K=1024, bf16 sources, global_load_lds staging, FP32 out.
// ---------------------------------------------------------------------------
__global__ __launch_bounds__(256) void out_gemm(
    const u16* __restrict__ A, const u16* __restrict__ W,
    float* __restrict__ O) {
  __shared__ u16 As[128 * 64];
  __shared__ u16 Bs[128 * 64];
  const int tid = threadIdx.x;
  const int lane = tid & 63;
  const int wv = tid >> 6;
  const int quad = lane >> 4;
  const int l16 = lane & 15;
  const int m0 = (wv >> 1) * 64;
  const int n0 = (wv & 1) * 64;
  const int rowA0 = blockIdx.y * 128;
  const int rowB0 = blockIdx.x * 128;

  f32x4 acc[4][4] = {};

  for (int kt = 0; kt < 1024; kt += 64) {
#pragma unroll
    for (int t = 0; t < 4; ++t) {
      int base = t * 256 + wv * 64;
      int idx = base + lane;
      int row = idx >> 3, c = (idx & 7) * 8;
      gll16(&A[(size_t)(rowA0 + row) * 1024 + kt + c], &As[base * 8]);
      gll16(&W[(size_t)(rowB0 + row) * 1024 + kt + c], &Bs[base * 8]);
    }
    __syncthreads();
#pragma unroll
    for (int kk = 0; kk < 64; kk += 32) {
      bf16x8 af[4], bfr[4];
#pragma unroll
      for (int i = 0; i < 4; ++i)
        af[i] = ldfrag(&As[(m0 + i * 16 + l16) * 64 + kk + quad * 8]);
#pragma unroll
      for (int j = 0; j < 4; ++j)
        bfr[j] = ldfrag(&Bs[(n0 + j * 16 + l16) * 64 + kk + quad * 8]);
#pragma unroll
      for (int i = 0; i < 4; ++i)
#pragma unroll
        for (int j = 0; j < 4; ++j)
          acc[i][j] = __builtin_amdgcn_mfma_f32_16x16x32_bf16(af[i], bfr[j], acc[i][j], 0, 0, 0);
    }
    __syncthreads();
  }

#pragma unroll
  for (int i = 0; i < 4; ++i)
#pragma unroll
    for (int j = 0; j < 4; ++j)
#pragma unroll
      for (int r = 0; r < 4; ++r) {
        int m = rowA0 + m0 + i * 16 + quad * 4 + r;
        int o = rowB0 + n0 + j * 16 + l16;
        O[(size_t)m * 1024 + o] = acc[i][j][r];   // fp32 out
      }
}

extern "C" void kernel_launch(void* const* d_in, const int* in_sizes, int n_in,
                              void* d_out, int out_size, void* d_ws, size_t ws_size,
                              hipStream_t stream) {
  (void)in_sizes; (void)n_in; (void)out_size; (void)ws_size;
  const float* x    = (const float*)d_in[0];   // [4,2048,1024] fp32
  const float* Wqkv = (const float*)d_in[1];   // [3072,1024]  fp32
  const float* Wout = (const float*)d_in[2];   // [1024,1024]  fp32
  float* out = (float*)d_out;                  // [4,2048,1024] fp32
  u16* ws = (u16*)d_ws;

  const size_t NX   = (size_t)4 * 2048 * 1024;  // 8,388,608
  const size_t NQKV = (size_t)3072 * 1024;      // 3,145,728
  const size_t NOUT = (size_t)1024 * 1024;      // 1,048,576
  const size_t SZ   = NX;

  u16* Xc    = ws;               // bf16 inputs
  u16* Wqkvc = Xc + NX;
  u16* Woutc = Wqkvc + NQKV;
  u16* Qw    = Woutc + NOUT;     // [B,H,T,D] bf16, pre-scaled 0.125*log2e
  u16* Kw    = Qw + SZ;          // [B,H,T,D] bf16
  u16* Vtw   = Kw + SZ;          // [B,H,D,T] bf16 (transposed)
  u16* Ao    = Vtw + SZ;         // [B,T,E]   bf16

  cvt_bf16<<<dim3(1024), 256, 0, stream>>>(x, Xc, (int)(NX / 8));
  cvt_bf16<<<dim3(384), 256, 0, stream>>>(Wqkv, Wqkvc, (int)(NQKV / 8));
  cvt_bf16<<<dim3(128), 256, 0, stream>>>(Wout, Woutc, (int)(NOUT / 8));

  qkv_gemm<<<dim3(24, 64), 256, 0, stream>>>(Xc, Wqkvc, Qw, Kw, Vtw);
  attn_kernel<<<dim3(4096), 64, 0, stream>>>(Qw, Kw, Vtw, Ao);
  out_gemm<<<dim3(8, 64), 256, 0, stream>>>(Ao, Woutc, out);
}

// Round 8
// 347.693 us; speedup vs baseline: 1.5590x; 1.0071x over previous
//
#include <hip/hip_runtime.h>

using u16 = unsigned short;
using u32 = unsigned int;
typedef __bf16 bf16;
typedef bf16 bf16x8 __attribute__((ext_vector_type(8)));
typedef u16 u16x8 __attribute__((ext_vector_type(8)));
typedef u16 u16x4 __attribute__((ext_vector_type(4)));
typedef u32 u32x2 __attribute__((ext_vector_type(2)));
typedef float f32x4 __attribute__((ext_vector_type(4)));

// Problem constants: B=4, T=2048, E=1024, H=16, D=64
// Inputs fp32, output fp32. Internals bf16 (MFMA).
#define LDSS 72   // padded stride, attn P buffer only (GEMM tiles are unpadded for global_load_lds)

__device__ __forceinline__ u16 f2bf(float f) {
  u32 u = __builtin_bit_cast(u32, f);
  u += 0x7FFFu + ((u >> 16) & 1u);   // round-to-nearest-even
  return (u16)(u >> 16);
}

// truncating pack: two fp32 -> two bf16 in ONE v_perm_b32 (softmax P only;
// trunc error <= 2^-8 relative, inside the absmax budget)
__device__ __forceinline__ u32 packtrunc(float lo, float hi) {
  return __builtin_amdgcn_perm(__builtin_bit_cast(u32, hi),
                               __builtin_bit_cast(u32, lo), 0x07060302u);
}

__device__ __forceinline__ float fexp2(float x) {
#if __has_builtin(__builtin_amdgcn_exp2f)
  return __builtin_amdgcn_exp2f(x);   // bare v_exp_f32 (args here are never denormal-critical)
#else
  return exp2f(x);
#endif
}

__device__ __forceinline__ bf16x8 ldfrag(const u16* p) {
  return __builtin_bit_cast(bf16x8, *(const u16x8*)p);
}

__device__ __forceinline__ u16x8 cvt8(const float* p) {
  float4 a = ((const float4*)p)[0];
  float4 b = ((const float4*)p)[1];
  u16x8 o;
  o[0] = f2bf(a.x); o[1] = f2bf(a.y); o[2] = f2bf(a.z); o[3] = f2bf(a.w);
  o[4] = f2bf(b.x); o[5] = f2bf(b.y); o[6] = f2bf(b.z); o[7] = f2bf(b.w);
  return o;
}

// async global->LDS, 16 B per lane; LDS dest = wave-uniform base + lane*16
__device__ __forceinline__ void gll16(const u16* g, u16* l) {
  __builtin_amdgcn_global_load_lds(
      (const __attribute__((address_space(1))) u32*)g,
      (__attribute__((address_space(3))) u32*)l, 16, 0, 0);
}

// ---------------------------------------------------------------------------
// fp32 -> bf16 convert (one-time; feeds global_load_lds GEMMs)
// ---------------------------------------------------------------------------
__global__ __launch_bounds__(256) void cvt_bf16(
    const float* __restrict__ src, u16* __restrict__ dst, int n8) {
  int i = blockIdx.x * 256 + threadIdx.x;
  const int stride = gridDim.x * 256;
  for (; i < n8; i += stride)
    ((u16x8*)dst)[i] = cvt8(&src[(size_t)i * 8]);
}

// ---------------------------------------------------------------------------
// QKV projection (m97-style): qkv[m][f] = sum_c x[m][c] * W_qkv[f][c]
// ---------------------------------------------------------------------------
__global__ __launch_bounds__(256) void qkv_gemm(
    const u16* __restrict__ X, const u16* __restrict__ W,
    u16* __restrict__ Qw, u16* __restrict__ Kw, u16* __restrict__ Vtw) {
  __shared__ u16 As[128 * 64];   // unpadded: required by global_load_lds layout
  __shared__ u16 Bs[128 * 64];
  const int tid = threadIdx.x;
  const int lane = tid & 63;
  const int wv = tid >> 6;
  const int quad = lane >> 4;
  const int l16 = lane & 15;
  const int m0 = (wv >> 1) * 64;
  const int n0 = (wv & 1) * 64;
  const int rowA0 = blockIdx.y * 128;
  const int rowB0 = blockIdx.x * 128;

  f32x4 acc[4][4] = {};

  for (int kt = 0; kt < 1024; kt += 64) {
#pragma unroll
    for (int t = 0; t < 4; ++t) {
      int base = t * 256 + wv * 64;        // wave-uniform chunk base
      int idx = base + lane;               // per-lane chunk (16 B)
      int row = idx >> 3, c = (idx & 7) * 8;
      gll16(&X[(size_t)(rowA0 + row) * 1024 + kt + c], &As[base * 8]);
      gll16(&W[(size_t)(rowB0 + row) * 1024 + kt + c], &Bs[base * 8]);
    }
    __syncthreads();
#pragma unroll
    for (int kk = 0; kk < 64; kk += 32) {
      bf16x8 af[4], bfr[4];
#pragma unroll
      for (int i = 0; i < 4; ++i)
        af[i] = ldfrag(&As[(m0 + i * 16 + l16) * 64 + kk + quad * 8]);
#pragma unroll
      for (int j = 0; j < 4; ++j)
        bfr[j] = ldfrag(&Bs[(n0 + j * 16 + l16) * 64 + kk + quad * 8]);
#pragma unroll
      for (int i = 0; i < 4; ++i)
#pragma unroll
        for (int j = 0; j < 4; ++j)
          acc[i][j] = __builtin_amdgcn_mfma_f32_16x16x32_bf16(af[i], bfr[j], acc[i][j], 0, 0, 0);
    }
    __syncthreads();
  }

  const float QSCALE = 0.125f * 1.4426950408889634f;  // D^-0.5 * log2(e)
#pragma unroll
  for (int i = 0; i < 4; ++i)
#pragma unroll
    for (int j = 0; j < 4; ++j)
#pragma unroll
      for (int r = 0; r < 4; ++r) {
        int m = rowA0 + m0 + i * 16 + quad * 4 + r;   // C row
        int f = rowB0 + n0 + j * 16 + l16;            // C col
        float v = acc[i][j][r];
        int bb = m >> 11, t = m & 2047;
        int part = f >> 10, fi = f & 1023;
        int h = fi >> 6, d = fi & 63;
        if (part == 0) {
          Qw[((size_t)(bb * 16 + h) * 2048 + t) * 64 + d] = f2bf(v * QSCALE);
        } else if (part == 1) {
          Kw[((size_t)(bb * 16 + h) * 2048 + t) * 64 + d] = f2bf(v);
        } else {
          Vtw[((size_t)(bb * 16 + h) * 64 + d) * 2048 + t] = f2bf(v);
        }
      }
}

// ---------------------------------------------------------------------------
// Flash attention, transposed-S, one wave per block (64 threads).
// Grid fully resident (4096 blocks = 256 CU x 16). Per-tile chain shortened:
// V-loads issued at loop top (hidden behind softmax), native exp2, v_perm
// truncating P-pack, wave-uniform alpha-skip.
// ---------------------------------------------------------------------------
__global__ __launch_bounds__(64) void attn_kernel(
    const u16* __restrict__ Qw, const u16* __restrict__ Kw,
    const u16* __restrict__ Vtw, u16* __restrict__ Ao) {
  __shared__ u16 pw[32 * LDSS];      // per-wave [q 32][key|d 64]
  const int lane = threadIdx.x & 63;
  const int quad = lane >> 4;
  const int l16 = lane & 15;
  const int s = 63 - (blockIdx.x >> 6);   // q-stripe
  const int bh = blockIdx.x & 63;
  const u16* Qb = Qw + (size_t)bh * 2048 * 64;
  const u16* Kb = Kw + (size_t)bh * 2048 * 64;
  const u16* Vb = Vtw + (size_t)bh * 64 * 2048;
  const int qrow0 = s * 32;

  // Q B-frags (n = q = l16, k = d = quad*8+j), held for the whole block
  bf16x8 qf[2][2];
#pragma unroll
  for (int i = 0; i < 2; ++i)
#pragma unroll
    for (int kk = 0; kk < 2; ++kk)
      qf[i][kk] = ldfrag(&Qb[(size_t)(qrow0 + i * 16 + l16) * 64 + kk * 32 + quad * 8]);

  f32x4 oacc[4][2] = {};          // O^T: [dblk][qblk]
  float mst[2] = {-INFINITY, -INFINITY};
  float lst[2] = {0.f, 0.f};

  const int nkt = (s >> 1) + 1;   // tiles covering keys <= qrow0+31
  for (int kt = 0; kt < nkt; ++kt) {
    const u16* Kt = Kb + (size_t)kt * 64 * 64;

    // issue K frags AND V frags up front: V consumed only after softmax,
    // so its latency hides behind ~600 VALU cycles.
    bf16x8 kf[2][4], vf[2][4];
#pragma unroll
    for (int kk = 0; kk < 2; ++kk)
#pragma unroll
      for (int j = 0; j < 4; ++j) {
        kf[kk][j] = ldfrag(&Kt[(size_t)(j * 16 + l16) * 64 + kk * 32 + quad * 8]);
        vf[kk][j] = ldfrag(&Vb[(size_t)(j * 16 + l16) * 2048 + kt * 64 + kk * 32 + quad * 8]);
      }

    // S^T = K . Q^T  (64 keys x 32 q)
    f32x4 sv[2][4] = {};           // [qblk][keyblk]
#pragma unroll
    for (int kk = 0; kk < 2; ++kk)
#pragma unroll
      for (int i = 0; i < 2; ++i)
#pragma unroll
        for (int j = 0; j < 4; ++j)
          sv[i][j] = __builtin_amdgcn_mfma_f32_16x16x32_bf16(kf[kk][j], qf[i][kk], sv[i][j], 0, 0, 0);

    // causal mask: key > q  (C-layout: row=key=quad*4+r, col=q=l16)
    if (kt * 64 + 63 > qrow0) {
#pragma unroll
      for (int i = 0; i < 2; ++i) {
        int q = qrow0 + i * 16 + l16;
#pragma unroll
        for (int j = 0; j < 4; ++j)
#pragma unroll
          for (int r = 0; r < 4; ++r)
            if (kt * 64 + j * 16 + quad * 4 + r > q) sv[i][j][r] = -INFINITY;
      }
    }

    // online softmax: per-lane q-column; cross-quad combine via 2 shuffles
#pragma unroll
    for (int i = 0; i < 2; ++i) {
      float mx = -INFINITY;
#pragma unroll
      for (int j = 0; j < 4; ++j)
#pragma unroll
        for (int r = 0; r < 4; ++r) mx = fmaxf(mx, sv[i][j][r]);
      mx = fmaxf(mx, __shfl_xor(mx, 16));
      mx = fmaxf(mx, __shfl_xor(mx, 32));
      float mnew = fmaxf(mst[i], mx);
      if (!__all(mnew == mst[i])) {      // wave-uniform: rescale only on max update
        float alpha = fexp2(mst[i] - mnew);
        lst[i] *= alpha;
#pragma unroll
        for (int d = 0; d < 4; ++d) oacc[d][i] *= alpha;
        mst[i] = mnew;
      }
      float rs = 0.f;
#pragma unroll
      for (int j = 0; j < 4; ++j) {
        float p0 = fexp2(sv[i][j][0] - mst[i]);
        float p1 = fexp2(sv[i][j][1] - mst[i]);
        float p2 = fexp2(sv[i][j][2] - mst[i]);
        float p3 = fexp2(sv[i][j][3] - mst[i]);
        rs += (p0 + p1) + (p2 + p3);
        u32x2 pk;
        pk[0] = packtrunc(p0, p1);
        pk[1] = packtrunc(p2, p3);
        // P^T row = q (i*16+l16), cols = 4 consecutive keys -> b64 write
        *(u32x2*)&pw[(i * 16 + l16) * LDSS + j * 16 + quad * 4] = pk;
      }
      rs += __shfl_xor(rs, 16);
      rs += __shfl_xor(rs, 32);
      lst[i] += rs;
    }

    // O^T += V^T . P^T   (A = V^T frags already resident, B = P^T from own LDS)
#pragma unroll
    for (int kk = 0; kk < 2; ++kk) {
      bf16x8 pf[2];
#pragma unroll
      for (int i = 0; i < 2; ++i)
        pf[i] = ldfrag(&pw[(i * 16 + l16) * LDSS + kk * 32 + quad * 8]);
#pragma unroll
      for (int d = 0; d < 4; ++d)
#pragma unroll
        for (int i = 0; i < 2; ++i)
          oacc[d][i] = __builtin_amdgcn_mfma_f32_16x16x32_bf16(vf[kk][d], pf[i], oacc[d][i], 0, 0, 0);
    }
  }

  // epilogue: O^T / l -> LDS transpose -> coalesced bf16 store to Ao [B,T,E]
  const int bb = bh >> 4, h = bh & 15;
#pragma unroll
  for (int i = 0; i < 2; ++i) {
    float inv = 1.f / lst[i];
#pragma unroll
    for (int d = 0; d < 4; ++d) {
      u16x4 ok;
#pragma unroll
      for (int r = 0; r < 4; ++r) ok[r] = f2bf(oacc[d][i][r] * inv);
      *(u16x4*)&pw[(i * 16 + l16) * LDSS + d * 16 + quad * 4] = ok;
    }
  }
  __builtin_amdgcn_s_waitcnt(0);   // lgkm drain (same-wave write->read)
  const int row = lane >> 1, half = lane & 1;
  const int t = qrow0 + row;
#pragma unroll
  for (int c = 0; c < 4; ++c) {
    u16x8 v = *(u16x8*)&pw[row * LDSS + half * 32 + c * 8];
    *(u16x8*)&Ao[((size_t)(bb * 2048 + t)) * 1024 + h * 64 + half * 32 + c * 8] = v;
  }
}

// ---------------------------------------------------------------------------
// Output projection (m97-style): out[m][o] = sum_c att[m][c] * W_out[o][c]
// ---------------------------------------------------------------------------
__global__ __launch_bounds__(256) void out_gemm(
    const u16* __restrict__ A, const u16* __restrict__ W,
    float* __restrict__ O) {
  __shared__ u16 As[128 * 64];
  __shared__ u16 Bs[128 * 64];
  const int tid = threadIdx.x;
  const int lane = tid & 63;
  const int wv = tid >> 6;
  const int quad = lane >> 4;
  const int l16 = lane & 15;
  const int m0 = (wv >> 1) * 64;
  const int n0 = (wv & 1) * 64;
  const int rowA0 = blockIdx.y * 128;
  const int rowB0 = blockIdx.x * 128;

  f32x4 acc[4][4] = {};

  for (int kt = 0; kt < 1024; kt += 64) {
#pragma unroll
    for (int t = 0; t < 4; ++t) {
      int base = t * 256 + wv * 64;
      int idx = base + lane;
      int row = idx >> 3, c = (idx & 7) * 8;
      gll16(&A[(size_t)(rowA0 + row) * 1024 + kt + c], &As[base * 8]);
      gll16(&W[(size_t)(rowB0 + row) * 1024 + kt + c], &Bs[base * 8]);
    }
    __syncthreads();
#pragma unroll
    for (int kk = 0; kk < 64; kk += 32) {
      bf16x8 af[4], bfr[4];
#pragma unroll
      for (int i = 0; i < 4; ++i)
        af[i] = ldfrag(&As[(m0 + i * 16 + l16) * 64 + kk + quad * 8]);
#pragma unroll
      for (int j = 0; j < 4; ++j)
        bfr[j] = ldfrag(&Bs[(n0 + j * 16 + l16) * 64 + kk + quad * 8]);
#pragma unroll
      for (int i = 0; i < 4; ++i)
#pragma unroll
        for (int j = 0; j < 4; ++j)
          acc[i][j] = __builtin_amdgcn_mfma_f32_16x16x32_bf16(af[i], bfr[j], acc[i][j], 0, 0, 0);
    }
    __syncthreads();
  }

#pragma unroll
  for (int i = 0; i < 4; ++i)
#pragma unroll
    for (int j = 0; j < 4; ++j)
#pragma unroll
      for (int r = 0; r < 4; ++r) {
        int m = rowA0 + m0 + i * 16 + quad * 4 + r;
        int o = rowB0 + n0 + j * 16 + l16;
        O[(size_t)m * 1024 + o] = acc[i][j][r];   // fp32 out
      }
}

extern "C" void kernel_launch(void* const* d_in, const int* in_sizes, int n_in,
                              void* d_out, int out_size, void* d_ws, size_t ws_size,
                              hipStream_t stream) {
  (void)in_sizes; (void)n_in; (void)out_size; (void)ws_size;
  const float* x    = (const float*)d_in[0];   // [4,2048,1024] fp32
  const float* Wqkv = (const float*)d_in[1];   // [3072,1024]  fp32
  const float* Wout = (const float*)d_in[2];   // [1024,1024]  fp32
  float* out = (float*)d_out;                  // [4,2048,1024] fp32
  u16* ws = (u16*)d_ws;

  const size_t NX   = (size_t)4 * 2048 * 1024;  // 8,388,608
  const size_t NQKV = (size_t)3072 * 1024;      // 3,145,728
  const size_t NOUT = (size_t)1024 * 1024;      // 1,048,576
  const size_t SZ   = NX;

  u16* Xc    = ws;               // bf16 inputs
  u16* Wqkvc = Xc + NX;
  u16* Woutc = Wqkvc + NQKV;
  u16* Qw    = Woutc + NOUT;     // [B,H,T,D] bf16, pre-scaled 0.125*log2e
  u16* Kw    = Qw + SZ;          // [B,H,T,D] bf16
  u16* Vtw   = Kw + SZ;          // [B,H,D,T] bf16 (transposed)
  u16* Ao    = Vtw + SZ;         // [B,T,E]   bf16

  cvt_bf16<<<dim3(1024), 256, 0, stream>>>(x, Xc, (int)(NX / 8));
  cvt_bf16<<<dim3(384), 256, 0, stream>>>(Wqkv, Wqkvc, (int)(NQKV / 8));
  cvt_bf16<<<dim3(128), 256, 0, stream>>>(Wout, Woutc, (int)(NOUT / 8));

  qkv_gemm<<<dim3(24, 64), 256, 0, stream>>>(Xc, Wqkvc, Qw, Kw, Vtw);
  attn_kernel<<<dim3(4096), 64, 0, stream>>>(Qw, Kw, Vtw, Ao);
  out_gemm<<<dim3(8, 64), 256, 0, stream>>>(Ao, Woutc, out);
}